// Round 13
// baseline (33.043 us; speedup 1.0000x reference)
//
#include <hip/hip_runtime.h>

typedef __attribute__((ext_vector_type(8))) short bf16x8;
typedef __attribute__((ext_vector_type(16))) float f32x16;

#define SLEN 2048
#define DDIM 64
#define NH 16
#define KEPS 1e-6f
#define TILE_B 16384          // bytes per (K 8KB | VT 8KB) tile image in ws

// packed fp32x2 -> bf16x2 RNE, single VALU op
__device__ __forceinline__ unsigned cvtpk(float lo, float hi) {
    unsigned r;
    asm("v_cvt_pk_bf16_f32 %0, %1, %2" : "=v"(r) : "v"(lo), "v"(hi));
    return r;
}
__device__ __forceinline__ f32x16 mfma32x32(bf16x8 a, bf16x8 b, f32x16 c) {
    return __builtin_amdgcn_mfma_f32_32x32x16_bf16(a, b, c, 0, 0, 0);
}
// async global->LDS, 16B per lane; LDS dest = wave-uniform base + lane*16
__device__ __forceinline__ void gload16(const void* g, void* l) {
    __builtin_amdgcn_global_load_lds(
        (const __attribute__((address_space(1))) unsigned*)g,
        (__attribute__((address_space(3))) unsigned*)l, 16, 0, 0);
}

// ---------------- prep: per-tile bf16 fragment images in ws (register transpose; proven) ----
// WS[h][kt] (16 KB): K chunks c=ks*2+hi: [c][j][8t] = bf16(K[h][kt*64+j][ks*16+hi*8+t])
//                    V (+8KB) chunks cv:  [cv][d][8j] = bf16(V[h][kt*64+cv*8+jj][d])
__global__ void __launch_bounds__(256) prep_kernel(
    const float* __restrict__ K, const float* __restrict__ V, char* __restrict__ WS)
{
    const int b  = blockIdx.x;            // h*32 + kt
    const int h  = b >> 5;
    const int kt = b & 31;
    const int t  = threadIdx.x;
    char* chunk = WS + (size_t)b * TILE_B;

    {   // K: row j = t>>2, cols (t&3)*16.. -> two 16B fragment writes
        const int j = t >> 2, ks = t & 3, c16 = ks * 16;
        const float* src = K + ((size_t)h * SLEN + kt * 64 + j) * DDIM + c16;
        float4 a = ((const float4*)src)[0], bb = ((const float4*)src)[1];
        float4 c = ((const float4*)src)[2], d = ((const float4*)src)[3];
        uint4 lo = make_uint4(cvtpk(a.x,a.y), cvtpk(a.z,a.w), cvtpk(bb.x,bb.y), cvtpk(bb.z,bb.w));
        uint4 hi = make_uint4(cvtpk(c.x,c.y), cvtpk(c.z,c.w), cvtpk(d.x,d.y), cvtpk(d.z,d.w));
        *(uint4*)(chunk + ((size_t)((ks*2+0)*64 + j)) * 16) = lo;
        *(uint4*)(chunk + ((size_t)((ks*2+1)*64 + j)) * 16) = hi;
    }
    {   // V: 4x4 register-block transpose
        const int j0 = (t & 15) * 4, d0 = (t >> 4) * 4;
        const float* vs = V + ((size_t)h * SLEN + kt * 64 + j0) * DDIM + d0;
        float4 r0 = *(const float4*)(vs);
        float4 r1 = *(const float4*)(vs + DDIM);
        float4 r2 = *(const float4*)(vs + 2 * DDIM);
        float4 r3 = *(const float4*)(vs + 3 * DDIM);
        char* vbase = chunk + 8192;
        const int cv  = j0 >> 3;
        const int tof = j0 & 7;           // 0 or 4
#pragma unroll
        for (int c = 0; c < 4; ++c) {
            uint2 pk = make_uint2(
                cvtpk(((const float*)&r0)[c], ((const float*)&r1)[c]),
                cvtpk(((const float*)&r2)[c], ((const float*)&r3)[c]));
            *(uint2*)(vbase + (size_t)(cv * 64 + d0 + c) * 16 + tof * 2) = pk;
        }
    }
}

// ---------------- main: async gload_lds double-buffer, spill-proof launch config ----------------
// 512 blocks x 256 threads. Block = (head h = bid&15 -> XCD-pinned, group g with
// bid<->bid+256 complementary). 4 waves = qhalf x jb; each wave: 32 q-rows x 32 j-cols
// of every 64-KV tile. Per tile: stage NEXT tile (16 KB) via global_load_lds into the
// other buffer, compute CURRENT from LDS (conflict-free ds_read_b128 fragment reads),
// ONE __syncthreads per tile (drains loads issued a full compute-phase earlier).
__global__ void __launch_bounds__(256) attn_main(
    const float* __restrict__ Q, const char* __restrict__ WS, float* __restrict__ O)
{
    __shared__ __align__(16) char smem[2][TILE_B];   // 32 KB double buffer (+reduction reuse)

    const int bid = blockIdx.x;
    const int h   = bid & 15;                // h&7 = bid&7 -> head pinned to XCD
    const int u   = bid >> 4;                // 0..31
    const int g   = (u < 16) ? u : (47 - u); // bid & bid+256 complementary work

    const int tid  = threadIdx.x;
    const int w    = tid >> 6;               // wave 0..3
    const int lane = tid & 63;
    const int il   = lane & 31;
    const int hi   = lane >> 5;
    const int qhalf = w >> 1;                // which 32-row half of the 64-row group
    const int jb    = w & 1;                 // j-subtile within 64-KV tile

    const int q0 = g * 64 + qhalf * 32;

    const float* __restrict__ Qh = Q + (size_t)h * SLEN * DDIM;
    float* __restrict__ Oh = O + (size_t)h * SLEN * DDIM;
    const char* __restrict__ WSh = WS + (size_t)h * 32 * TILE_B;

    // ---- Q fragments (B-frag of 32x32x16): lane holds Q[q0+il][ks*16+hi*8+t] ----
    bf16x8 qf[4];
#pragma unroll
    for (int ks = 0; ks < 4; ++ks) {
        const float* src = Qh + (size_t)(q0 + il) * DDIM + ks * 16 + hi * 8;
        float4 a = *reinterpret_cast<const float4*>(src);
        float4 b = *reinterpret_cast<const float4*>(src + 4);
        uint4 uq = make_uint4(cvtpk(a.x, a.y), cvtpk(a.z, a.w),
                              cvtpk(b.x, b.y), cvtpk(b.z, b.w));
        qf[ks] = *reinterpret_cast<bf16x8*>(&uq);
    }

    f32x16 o0, o1;
#pragma unroll
    for (int rr = 0; rr < 16; ++rr) { o0[rr] = 0.f; o1[rr] = 0.f; }
    float z = 0.f;

    // staging: thread copies 4 x 16B at stride 1024 (linear tile image copy)
    auto stage = [&](int buf, int kt) {
        const char* gs = WSh + (size_t)kt * TILE_B + w * 4096 + lane * 16;
        char* ls = &smem[buf][w * 4096];
#pragma unroll
        for (int i = 0; i < 4; ++i)
            gload16(gs + i * 1024, ls + i * 1024);
    };

    // per-lane byte offsets within a tile image
    const int kbase = (jb * 32 + il) * 16;                        // + (ks*2+hi)*1024
    const int vbase = 8192 + (jb * 4 + hi) * 1024 + il * 16;      // + s16*2048 + dt*512

    const int ktend = g - ((jb > qhalf) ? 1 : 0);   // jb>qhalf: diagonal tile fully masked

    // ---- prologue: stage tile 0 ----
    stage(0, 0);
    __syncthreads();

    for (int kt = 0; kt <= g; ++kt) {
        const int cur = kt & 1;
        if (kt < g) stage(cur ^ 1, kt + 1);    // async: drains at this iter's barrier

        if (kt <= ktend) {
            const char* base = smem[cur];
            bf16x8 kf0 = *(const bf16x8*)(base + 0 * 1024 + hi * 1024 + kbase);
            bf16x8 kf1 = *(const bf16x8*)(base + 2 * 1024 + hi * 1024 + kbase);
            bf16x8 kf2 = *(const bf16x8*)(base + 4 * 1024 + hi * 1024 + kbase);
            bf16x8 kf3 = *(const bf16x8*)(base + 6 * 1024 + hi * 1024 + kbase);

            __builtin_amdgcn_s_setprio(1);
            f32x16 sv;
#pragma unroll
            for (int rr = 0; rr < 16; ++rr) sv[rr] = 0.f;
            sv = mfma32x32(kf0, qf[0], sv);
            sv = mfma32x32(kf1, qf[1], sv);
            sv = mfma32x32(kf2, qf[2], sv);
            sv = mfma32x32(kf3, qf[3], sv);
            __builtin_amdgcn_s_setprio(0);

            // lane: S^T[j=(rr&3)+8*(rr>>2)+4*hi][i=il]; pv = (s/8)^2 = s^2/64
            const bool tri = (kt == g) && (jb == qhalf);
#pragma unroll
            for (int rr = 0; rr < 16; ++rr) {
                float x = sv[rr];
                x = x * x * 0.015625f;
                if (tri) {
                    int jl = (rr & 3) + 8 * (rr >> 2) + 4 * hi;
                    if (jl > il) x = 0.f;
                }
                sv[rr] = x;
            }
            {
                float a0 = (sv[0] + sv[1]) + (sv[2] + sv[3]);
                float a1 = (sv[4] + sv[5]) + (sv[6] + sv[7]);
                float a2 = (sv[8] + sv[9]) + (sv[10] + sv[11]);
                float a3 = (sv[12] + sv[13]) + (sv[14] + sv[15]);
                z += (a0 + a1) + (a2 + a3);
            }

            // pack P (cvt_pk + permlane32_swap), PV MFMAs with LDS V-frags
            __builtin_amdgcn_s_setprio(1);
            {
                unsigned X  = cvtpk(sv[0], sv[1]);
                unsigned Xp = cvtpk(sv[2], sv[3]);
                unsigned Y  = cvtpk(sv[4], sv[5]);
                unsigned Yp = cvtpk(sv[6], sv[7]);
                asm("v_permlane32_swap_b32 %0, %1" : "+v"(X), "+v"(Y));
                asm("v_permlane32_swap_b32 %0, %1" : "+v"(Xp), "+v"(Yp));
                uint4 aw = make_uint4(X, Xp, Y, Yp);
                bf16x8 pf = *reinterpret_cast<bf16x8*>(&aw);
                bf16x8 va = *(const bf16x8*)(base + vbase + 0 * 2048 + 0 * 512);
                bf16x8 vb = *(const bf16x8*)(base + vbase + 0 * 2048 + 1 * 512);
                o0 = mfma32x32(pf, va, o0);
                o1 = mfma32x32(pf, vb, o1);
            }
            {
                unsigned X  = cvtpk(sv[8],  sv[9]);
                unsigned Xp = cvtpk(sv[10], sv[11]);
                unsigned Y  = cvtpk(sv[12], sv[13]);
                unsigned Yp = cvtpk(sv[14], sv[15]);
                asm("v_permlane32_swap_b32 %0, %1" : "+v"(X), "+v"(Y));
                asm("v_permlane32_swap_b32 %0, %1" : "+v"(Xp), "+v"(Yp));
                uint4 aw = make_uint4(X, Xp, Y, Yp);
                bf16x8 pf = *reinterpret_cast<bf16x8*>(&aw);
                bf16x8 va = *(const bf16x8*)(base + vbase + 1 * 2048 + 0 * 512);
                bf16x8 vb = *(const bf16x8*)(base + vbase + 1 * 2048 + 1 * 512);
                o0 = mfma32x32(pf, va, o0);
                o1 = mfma32x32(pf, vb, o1);
            }
            __builtin_amdgcn_s_setprio(0);
        }

        __syncthreads();    // drains this iter's stage loads; flips buffer
    }

    // ---- combine jb pairs per qhalf via LDS (reuse smem; stride-33 floats) ----
    z += __shfl_xor(z, 32);                  // fold hi halves: z partial for row q0+il
    float* red = (float*)smem;
    if (jb == 1) {
        float* r = red + (size_t)((qhalf * 64 + lane) * 33);
#pragma unroll
        for (int rr = 0; rr < 16; ++rr) { r[rr] = o0[rr]; r[16 + rr] = o1[rr]; }
        r[32] = z;
    }
    __syncthreads();
    if (jb == 0) {
        const float* r = red + (size_t)((qhalf * 64 + lane) * 33);
#pragma unroll
        for (int rr = 0; rr < 16; ++rr) { o0[rr] += r[rr]; o1[rr] += r[16 + rr]; }
        z += r[32];

        const float invl = 1.f / (z + KEPS);    // lane il: inv for row q0+il
#pragma unroll
        for (int rr = 0; rr < 16; ++rr) {
            const int rl = (rr & 3) + 8 * (rr >> 2) + 4 * hi;
            const float inv = __shfl(invl, rl);
            Oh[(size_t)(q0 + rl) * DDIM + il]      = o0[rr] * inv;
            Oh[(size_t)(q0 + rl) * DDIM + 32 + il] = o1[rr] * inv;
        }
    }
}

// ---- correctness-only fallback when ws is unavailable ----
__global__ void __launch_bounds__(256) attn_fp32(
    const float* __restrict__ Q, const float* __restrict__ K,
    const float* __restrict__ V, float* __restrict__ O)
{
    __shared__ float red[2][64][33];
    const int bid = blockIdx.x;
    const int h   = bid & 15;
    const int u   = bid >> 4;
    const int g   = (u < 16) ? u : (47 - u);
    const int tid  = threadIdx.x;
    const int w    = tid >> 6;
    const int lane = tid & 63;
    const int il   = lane & 31;
    const int hi   = lane >> 5;
    const int qhalf = w >> 1;
    const int jb    = w & 1;
    const int q0 = g * 64 + qhalf * 32;

    const float* Qh = Q + (size_t)h * SLEN * DDIM;
    const float* Kh = K + (size_t)h * SLEN * DDIM;
    const float* Vh = V + (size_t)h * SLEN * DDIM;
    float* Oh = O + (size_t)h * SLEN * DDIM;

    bf16x8 qf[4];
#pragma unroll
    for (int ks = 0; ks < 4; ++ks) {
        const float* src = Qh + (size_t)(q0 + il) * DDIM + ks * 16 + hi * 8;
        float4 a = *reinterpret_cast<const float4*>(src);
        float4 b = *reinterpret_cast<const float4*>(src + 4);
        uint4 uq = make_uint4(cvtpk(a.x, a.y), cvtpk(a.z, a.w),
                              cvtpk(b.x, b.y), cvtpk(b.z, b.w));
        qf[ks] = *reinterpret_cast<bf16x8*>(&uq);
    }
    f32x16 o0, o1;
#pragma unroll
    for (int rr = 0; rr < 16; ++rr) { o0[rr] = 0.f; o1[rr] = 0.f; }
    float z = 0.f;
    const int ktend = g - ((jb > qhalf) ? 1 : 0);

    for (int kt = 0; kt <= ktend; ++kt) {
        f32x16 sv;
#pragma unroll
        for (int rr = 0; rr < 16; ++rr) sv[rr] = 0.f;
#pragma unroll
        for (int ks = 0; ks < 4; ++ks) {
            const float* src = Kh + (size_t)(kt * 64 + jb * 32 + il) * DDIM + ks * 16 + hi * 8;
            float4 a = *reinterpret_cast<const float4*>(src);
            float4 b = *reinterpret_cast<const float4*>(src + 4);
            uint4 uk = make_uint4(cvtpk(a.x, a.y), cvtpk(a.z, a.w),
                                  cvtpk(b.x, b.y), cvtpk(b.z, b.w));
            sv = mfma32x32(*reinterpret_cast<bf16x8*>(&uk), qf[ks], sv);
        }
        const bool tri = (kt == g) && (jb == qhalf);
#pragma unroll
        for (int rr = 0; rr < 16; ++rr) {
            float x = sv[rr];
            x = x * x * 0.015625f;
            if (tri) {
                int jl = (rr & 3) + 8 * (rr >> 2) + 4 * hi;
                if (jl > il) x = 0.f;
            }
            sv[rr] = x;
            z += x;
        }
#pragma unroll
        for (int s16 = 0; s16 < 2; ++s16) {
            unsigned X  = cvtpk(sv[8*s16+0], sv[8*s16+1]);
            unsigned Xp = cvtpk(sv[8*s16+2], sv[8*s16+3]);
            unsigned Y  = cvtpk(sv[8*s16+4], sv[8*s16+5]);
            unsigned Yp = cvtpk(sv[8*s16+6], sv[8*s16+7]);
            asm("v_permlane32_swap_b32 %0, %1" : "+v"(X), "+v"(Y));
            asm("v_permlane32_swap_b32 %0, %1" : "+v"(Xp), "+v"(Yp));
            uint4 aw = make_uint4(X, Xp, Y, Yp);
            bf16x8 pf = *reinterpret_cast<bf16x8*>(&aw);
#pragma unroll
            for (int dt = 0; dt < 2; ++dt) {
                float v8[8];
#pragma unroll
                for (int t = 0; t < 8; ++t)
                    v8[t] = Vh[(size_t)(kt * 64 + jb * 32 + s16 * 16 + hi * 8 + t) * DDIM + dt * 32 + il];
                uint4 uv = make_uint4(cvtpk(v8[0], v8[1]), cvtpk(v8[2], v8[3]),
                                      cvtpk(v8[4], v8[5]), cvtpk(v8[6], v8[7]));
                bf16x8 vf = *reinterpret_cast<bf16x8*>(&uv);
                if (dt == 0) o0 = mfma32x32(pf, vf, o0);
                else         o1 = mfma32x32(pf, vf, o1);
            }
        }
    }

    z += __shfl_xor(z, 32);
    if (jb == 1) {
        float* r = &red[qhalf][lane][0];
#pragma unroll
        for (int rr = 0; rr < 16; ++rr) { r[rr] = o0[rr]; r[16 + rr] = o1[rr]; }
        r[32] = z;
    }
    __syncthreads();
    if (jb == 0) {
        const float* r = &red[qhalf][lane][0];
#pragma unroll
        for (int rr = 0; rr < 16; ++rr) { o0[rr] += r[rr]; o1[rr] += r[16 + rr]; }
        z += r[32];
        const float invl = 1.f / (z + KEPS);
#pragma unroll
        for (int rr = 0; rr < 16; ++rr) {
            const int rl = (rr & 3) + 8 * (rr >> 2) + 4 * hi;
            const float inv = __shfl(invl, rl);
            Oh[(size_t)(q0 + rl) * DDIM + il]      = o0[rr] * inv;
            Oh[(size_t)(q0 + rl) * DDIM + 32 + il] = o1[rr] * inv;
        }
    }
}

extern "C" void kernel_launch(void* const* d_in, const int* in_sizes, int n_in,
                              void* d_out, int out_size, void* d_ws, size_t ws_size,
                              hipStream_t stream) {
    const float* q = (const float*)d_in[0];
    const float* k = (const float*)d_in[1];
    const float* v = (const float*)d_in[2];
    float* o = (float*)d_out;

    const size_t need = (size_t)NH * 32 * TILE_B;   // 8 MB
    if (ws_size >= need) {
        char* ws = (char*)d_ws;
        hipLaunchKernelGGL(prep_kernel, dim3(NH * 32), dim3(256), 0, stream, k, v, ws);
        hipLaunchKernelGGL(attn_main, dim3(512), dim3(256), 0, stream, q, ws, o);
    } else {
        hipLaunchKernelGGL(attn_fp32, dim3(512), dim3(256), 0, stream, q, k, v, o);
    }
}